// Round 1
// baseline (359.645 us; speedup 1.0000x reference)
//
#include <hip/hip_runtime.h>
#include <hip/hip_bf16.h>

// Problem constants: x is (B=32, C=256, H=64, W=64) fp32.
#define NB 32
#define NC 256
#define NH 64
#define NW 64
#define HW (NH * NW)          // 4096
#define CHW (NC * NH * NW)    // 1048576

// Workspace layout (float offsets). Total ~3.43M floats = 13.1 MB.
static constexpr size_t OFF_HSUM = 0;                         // [B][C][H]
static constexpr size_t OFF_WSUM = OFF_HSUM + (size_t)NB*NC*NH; // [B][C][W]
static constexpr size_t OFF_CSUM = OFF_WSUM + (size_t)NB*NC*NW; // [B][C]
static constexpr size_t OFF_VSP  = OFF_CSUM + (size_t)NB*NC;    // [B][C]
static constexpr size_t OFF_VH   = OFF_VSP  + (size_t)NB*NC;    // [B][H]
static constexpr size_t OFF_VW   = OFF_VH   + (size_t)NB*NH;    // [B][W]
static constexpr size_t OFF_SSP  = OFF_VW   + (size_t)NB*NW;    // [B][HW]
static constexpr size_t OFF_SH   = OFF_SSP  + (size_t)NB*HW;    // [B][C][W]
static constexpr size_t OFF_SW   = OFF_SH   + (size_t)NB*NC*NW; // [B][H][C]
static constexpr size_t OFF_PSP  = OFF_SW   + (size_t)NB*NH*NC; // [B][HW]
static constexpr size_t OFF_PSH  = OFF_PSP  + (size_t)NB*HW;    // [B][C][W]
static constexpr size_t OFF_PSW  = OFF_PSH  + (size_t)NB*NC*NW; // [B][H][C]

// ---------------------------------------------------------------------------
// K1: one pass over x. Block = one (b,c) 64x64 plane (8192 blocks, 256 thr).
// Produces raw sums: csum[b][c] (plane), hsum[b][c][h] (over w), wsum[b][c][w]
// (over h). Thread t loads 4 float4s: rows h0, h0+16, h0+32, h0+48 at column
// group w4 = t&15.
// ---------------------------------------------------------------------------
__global__ __launch_bounds__(256) void k_stats(const float* __restrict__ x,
                                               float* __restrict__ ws) {
    const int bc = blockIdx.x;         // b*256 + c
    const int t  = threadIdx.x;
    const float4* plane = reinterpret_cast<const float4*>(x) + ((size_t)bc << 10);
    const float4 v0 = plane[t];
    const float4 v1 = plane[t + 256];
    const float4 v2 = plane[t + 512];
    const float4 v3 = plane[t + 768];
    const int h0 = t >> 4;             // 0..15

    // ---- row (h) sums: reduce across the 16 consecutive lanes sharing h ----
    float hp0 = v0.x + v0.y + v0.z + v0.w;
    float hp1 = v1.x + v1.y + v1.z + v1.w;
    float hp2 = v2.x + v2.y + v2.z + v2.w;
    float hp3 = v3.x + v3.y + v3.z + v3.w;
    #pragma unroll
    for (int d = 1; d < 16; d <<= 1) {
        hp0 += __shfl_xor(hp0, d);
        hp1 += __shfl_xor(hp1, d);
        hp2 += __shfl_xor(hp2, d);
        hp3 += __shfl_xor(hp3, d);
    }
    if ((t & 15) == 0) {
        float* hdst = ws + OFF_HSUM + (size_t)bc * NH;
        hdst[h0]      = hp0;
        hdst[h0 + 16] = hp1;
        hdst[h0 + 32] = hp2;
        hdst[h0 + 48] = hp3;
    }

    // ---- column (w) sums: LDS tree over the 16 threads sharing w4 ----
    float4 wp;
    wp.x = v0.x + v1.x + v2.x + v3.x;
    wp.y = v0.y + v1.y + v2.y + v3.y;
    wp.z = v0.z + v1.z + v2.z + v3.z;
    wp.w = v0.w + v1.w + v2.w + v3.w;
    __shared__ float4 red4[256];
    red4[t] = wp;
    __syncthreads();
    for (int s2 = 128; s2 >= 16; s2 >>= 1) {
        if (t < s2) {
            red4[t].x += red4[t + s2].x;
            red4[t].y += red4[t + s2].y;
            red4[t].z += red4[t + s2].z;
            red4[t].w += red4[t + s2].w;
        }
        __syncthreads();
    }
    if (t < 16) {
        reinterpret_cast<float4*>(ws + OFF_WSUM + (size_t)bc * NW)[t] = red4[t];
    }
    // ---- plane sum from the 16 surviving column-group sums ----
    if (t == 0) {
        float s = 0.f;
        #pragma unroll
        for (int i = 0; i < 16; ++i)
            s += red4[i].x + red4[i].y + red4[i].z + red4[i].w;
        ws[OFF_CSUM + bc] = s;
    }
}

// ---------------------------------------------------------------------------
// K2: tiny per-b kernel (32 blocks, 256 thr). Finishes means and computes the
// per-axis weight vectors:
//   v_sp[b][c] = (w_left1 @ xbar_c) @ w_left2
//   v_h [b][h] = (w_right1 @ xbar_h) @ w_right2
//   v_w [b][w] = (w_right1 @ xbar_w) @ w_right2
// ---------------------------------------------------------------------------
__global__ __launch_bounds__(256) void k_vecs(const float* __restrict__ wl1,
                                              const float* __restrict__ wl2,
                                              const float* __restrict__ wr1,
                                              const float* __restrict__ wr2,
                                              float* __restrict__ ws) {
    const int b = blockIdx.x, t = threadIdx.x;
    __shared__ float xbc[256], xbh[64], xbw[64], x2sp[128], th[32], tw[32];
    __shared__ float red[256];

    xbc[t] = ws[OFF_CSUM + (size_t)b * NC + t] * (1.0f / 4096.0f);

    // xbar_h: sum hsum over c
    {
        const int h = t & 63, part = t >> 6;
        float s = 0.f;
        const float* hs = ws + OFF_HSUM + ((size_t)b * NC + part * 64) * NH + h;
        for (int c = 0; c < 64; ++c) s += hs[(size_t)c * NH];
        red[t] = s;
        __syncthreads();
        if (t < 64) xbh[t] = (red[t] + red[t + 64] + red[t + 128] + red[t + 192]) * (1.0f / 16384.0f);
        __syncthreads();
    }
    // xbar_w: sum wsum over c
    {
        const int w = t & 63, part = t >> 6;
        float s = 0.f;
        const float* wsrc = ws + OFF_WSUM + ((size_t)b * NC + part * 64) * NW + w;
        for (int c = 0; c < 64; ++c) s += wsrc[(size_t)c * NW];
        red[t] = s;
        __syncthreads();
        if (t < 64) xbw[t] = (red[t] + red[t + 64] + red[t + 128] + red[t + 192]) * (1.0f / 16384.0f);
        __syncthreads();
    }

    if (t < 128) {
        float a = 0.f;
        for (int c = 0; c < 256; ++c) a += wl1[t * 256 + c] * xbc[c];
        x2sp[t] = a;
    } else if (t < 160) {
        const int m = t - 128;
        float a = 0.f;
        for (int h = 0; h < 64; ++h) a += wr1[m * 64 + h] * xbh[h];
        th[m] = a;
    } else if (t < 192) {
        const int m = t - 160;
        float a = 0.f;
        for (int h = 0; h < 64; ++h) a += wr1[m * 64 + h] * xbw[h];
        tw[m] = a;
    }
    __syncthreads();

    {
        float a = 0.f;
        for (int m = 0; m < 128; ++m) a += x2sp[m] * wl2[m * 256 + t];
        ws[OFF_VSP + (size_t)b * NC + t] = a;
    }
    if (t < 64) {
        float a = 0.f;
        for (int m = 0; m < 32; ++m) a += th[m] * wr2[m * 64 + t];
        ws[OFF_VH + (size_t)b * NH + t] = a;
    } else if (t < 128) {
        const int w = t - 64;
        float a = 0.f;
        for (int m = 0; m < 32; ++m) a += tw[m] * wr2[m * 64 + w];
        ws[OFF_VW + (size_t)b * NW + w] = a;
    }
}

// ---------------------------------------------------------------------------
// K3: second pass over x.
//   blocks [0,8192): plane blocks -> s_h[b][c][w] = sum_h v_h*x,
//                                    s_w[b][h][c] = sum_w v_w*x
//   blocks [8192,8320): (b, quarter) column blocks ->
//                                    s_sp[b][n] = sum_c v_sp*x
// ---------------------------------------------------------------------------
__global__ __launch_bounds__(256) void k_scores(const float* __restrict__ x,
                                                float* __restrict__ ws) {
    const int t = threadIdx.x;
    if (blockIdx.x < 8192) {
        const int bc = blockIdx.x;
        const int b = bc >> 8, c = bc & 255;
        __shared__ float vh_s[64], vw_s[64];
        if (t < 64)        vh_s[t]      = ws[OFF_VH + (size_t)b * NH + t];
        else if (t < 128)  vw_s[t - 64] = ws[OFF_VW + (size_t)b * NW + (t - 64)];
        __syncthreads();

        const float4* plane = reinterpret_cast<const float4*>(x) + ((size_t)bc << 10);
        const float4 v0 = plane[t];
        const float4 v1 = plane[t + 256];
        const float4 v2 = plane[t + 512];
        const float4 v3 = plane[t + 768];
        const int h0 = t >> 4, w4 = t & 15;

        // s_w: per h, dot over w. shfl-reduce over 16 lanes sharing h.
        const float4 vwv = reinterpret_cast<const float4*>(vw_s)[w4];
        float hp0 = vwv.x * v0.x + vwv.y * v0.y + vwv.z * v0.z + vwv.w * v0.w;
        float hp1 = vwv.x * v1.x + vwv.y * v1.y + vwv.z * v1.z + vwv.w * v1.w;
        float hp2 = vwv.x * v2.x + vwv.y * v2.y + vwv.z * v2.z + vwv.w * v2.w;
        float hp3 = vwv.x * v3.x + vwv.y * v3.y + vwv.z * v3.z + vwv.w * v3.w;
        #pragma unroll
        for (int d = 1; d < 16; d <<= 1) {
            hp0 += __shfl_xor(hp0, d);
            hp1 += __shfl_xor(hp1, d);
            hp2 += __shfl_xor(hp2, d);
            hp3 += __shfl_xor(hp3, d);
        }
        if ((t & 15) == 0) {
            float* dst = ws + OFF_SW + (size_t)b * NH * NC + c;
            dst[(size_t)(h0)      * NC] = hp0;
            dst[(size_t)(h0 + 16) * NC] = hp1;
            dst[(size_t)(h0 + 32) * NC] = hp2;
            dst[(size_t)(h0 + 48) * NC] = hp3;
        }

        // s_h: per w, weighted sum over h. LDS tree over 16 threads per w4.
        const float a0 = vh_s[h0], a1 = vh_s[h0 + 16], a2 = vh_s[h0 + 32], a3 = vh_s[h0 + 48];
        float4 wp;
        wp.x = a0 * v0.x + a1 * v1.x + a2 * v2.x + a3 * v3.x;
        wp.y = a0 * v0.y + a1 * v1.y + a2 * v2.y + a3 * v3.y;
        wp.z = a0 * v0.z + a1 * v1.z + a2 * v2.z + a3 * v3.z;
        wp.w = a0 * v0.w + a1 * v1.w + a2 * v2.w + a3 * v3.w;
        __shared__ float4 red4[256];
        red4[t] = wp;
        __syncthreads();
        for (int s2 = 128; s2 >= 16; s2 >>= 1) {
            if (t < s2) {
                red4[t].x += red4[t + s2].x;
                red4[t].y += red4[t + s2].y;
                red4[t].z += red4[t + s2].z;
                red4[t].w += red4[t + s2].w;
            }
            __syncthreads();
        }
        if (t < 16) {
            reinterpret_cast<float4*>(ws + OFF_SH + (size_t)bc * NW)[t] = red4[t];
        }
    } else {
        // s_sp path: 128 blocks = (b, quarter-of-spatial)
        const int idx = blockIdx.x - 8192;
        const int b = idx >> 2, tile = idx & 3;
        __shared__ float vsp[256];
        vsp[t] = ws[OFF_VSP + (size_t)b * NC + t];
        __syncthreads();
        const float4* xb = reinterpret_cast<const float4*>(x) + ((size_t)b << 18);
        const int n4 = tile * 256 + t;
        float4 acc = make_float4(0.f, 0.f, 0.f, 0.f);
        #pragma unroll 4
        for (int c = 0; c < 256; ++c) {
            const float4 xv = xb[(size_t)c * 1024 + n4];
            const float vc = vsp[c];
            acc.x += vc * xv.x;
            acc.y += vc * xv.y;
            acc.z += vc * xv.z;
            acc.w += vc * xv.w;
        }
        reinterpret_cast<float4*>(ws + OFF_SSP + (size_t)b * HW)[n4] = acc;
    }
}

// ---------------------------------------------------------------------------
// K4: softmax + sigmoid per (branch, b). 96 blocks. Data stays in L2.
// ---------------------------------------------------------------------------
__global__ __launch_bounds__(256) void k_softmax(float* __restrict__ ws) {
    const int blk = blockIdx.x, t = threadIdx.x;
    const int kind = blk >> 5, b = blk & 31;
    const float* src;
    float* dst;
    int N;
    if (kind == 0)      { src = ws + OFF_SSP + (size_t)b * HW;      dst = ws + OFF_PSP + (size_t)b * HW;      N = HW; }
    else if (kind == 1) { src = ws + OFF_SH  + (size_t)b * NC * NW; dst = ws + OFF_PSH + (size_t)b * NC * NW; N = NC * NW; }
    else                { src = ws + OFF_SW  + (size_t)b * NH * NC; dst = ws + OFF_PSW + (size_t)b * NH * NC; N = NH * NC; }

    __shared__ float red[256];
    float mx = -3.4e38f;
    for (int i = t; i < N; i += 256) mx = fmaxf(mx, src[i]);
    red[t] = mx;
    __syncthreads();
    for (int s = 128; s > 0; s >>= 1) {
        if (t < s) red[t] = fmaxf(red[t], red[t + s]);
        __syncthreads();
    }
    mx = red[0];
    __syncthreads();

    float sm = 0.f;
    for (int i = t; i < N; i += 256) sm += expf(src[i] - mx);
    red[t] = sm;
    __syncthreads();
    for (int s = 128; s > 0; s >>= 1) {
        if (t < s) red[t] += red[t + s];
        __syncthreads();
    }
    const float inv = 1.0f / red[0];

    for (int i = t; i < N; i += 256) {
        const float p = expf(src[i] - mx) * inv;
        dst[i] = 1.0f / (1.0f + expf(-p));
    }
}

// ---------------------------------------------------------------------------
// K5: out = x * (p_sp[b][h][w] + p_h[b][c][w] + p_w[b][h][c]). float4 stride.
// ---------------------------------------------------------------------------
__global__ __launch_bounds__(256) void k_final(const float* __restrict__ x,
                                               const float* __restrict__ ws,
                                               float* __restrict__ out) {
    const float* psp = ws + OFF_PSP;
    const float* psh = ws + OFF_PSH;
    const float* psw = ws + OFF_PSW;
    const size_t total4 = (size_t)NB * CHW / 4;  // 8388608
    for (size_t i4 = (size_t)blockIdx.x * 256 + threadIdx.x; i4 < total4;
         i4 += (size_t)gridDim.x * 256) {
        const int w4 = (int)(i4 & 15);
        const int h  = (int)((i4 >> 4) & 63);
        const int c  = (int)((i4 >> 10) & 255);
        const int b  = (int)(i4 >> 18);
        const float4 xv = reinterpret_cast<const float4*>(x)[i4];
        const float4 sp = reinterpret_cast<const float4*>(psp)[((size_t)b << 10) + (h << 4) + w4];
        const float4 sh = reinterpret_cast<const float4*>(psh)[(((size_t)b << 8) + c) * 16 + w4];
        const float  sw = psw[((size_t)b << 14) + (h << 8) + c];
        float4 o;
        o.x = xv.x * (sp.x + sh.x + sw);
        o.y = xv.y * (sp.y + sh.y + sw);
        o.z = xv.z * (sp.z + sh.z + sw);
        o.w = xv.w * (sp.w + sh.w + sw);
        reinterpret_cast<float4*>(out)[i4] = o;
    }
}

extern "C" void kernel_launch(void* const* d_in, const int* in_sizes, int n_in,
                              void* d_out, int out_size, void* d_ws, size_t ws_size,
                              hipStream_t stream) {
    const float* x   = (const float*)d_in[0];
    const float* wl1 = (const float*)d_in[1];
    const float* wl2 = (const float*)d_in[2];
    const float* wr1 = (const float*)d_in[3];
    const float* wr2 = (const float*)d_in[4];
    float* out = (float*)d_out;
    float* ws  = (float*)d_ws;

    k_stats  <<<NB * NC, 256, 0, stream>>>(x, ws);
    k_vecs   <<<NB, 256, 0, stream>>>(wl1, wl2, wr1, wr2, ws);
    k_scores <<<NB * NC + NB * 4, 256, 0, stream>>>(x, ws);
    k_softmax<<<3 * NB, 256, 0, stream>>>(ws);
    k_final  <<<2048, 256, 0, stream>>>(x, ws, out);
}

// Round 9
// 332.081 us; speedup vs baseline: 1.0830x; 1.0830x over previous
//
#include <hip/hip_runtime.h>

// x is (B=32, C=256, H=64, W=64) fp32.
#define NB 32
#define NC 256
#define NH 64
#define NW 64
#define HW (NH * NW)          // 4096

// Native 4-float vector for __builtin_nontemporal_store (HIP float4 is a
// class type the builtin rejects; this is layout-identical).
typedef float nfloat4 __attribute__((ext_vector_type(4)));

// Workspace layout (float offsets). Total ~7.5M floats = 30 MB.
static constexpr size_t OFF_HSUM = 0;                           // [B][C][H]
static constexpr size_t OFF_WSUM = OFF_HSUM + (size_t)NB*NC*NH; // [B][C][W]
static constexpr size_t OFF_CSUM = OFF_WSUM + (size_t)NB*NC*NW; // [B][C]
static constexpr size_t OFF_VSP  = OFF_CSUM + (size_t)NB*NC;    // [B][C]
static constexpr size_t OFF_VH   = OFF_VSP  + (size_t)NB*NC;    // [B][H]
static constexpr size_t OFF_VW   = OFF_VH   + (size_t)NB*NH;    // [B][W]
static constexpr size_t OFF_SH   = OFF_VW   + (size_t)NB*NW;    // [B][C][W]
static constexpr size_t OFF_SW   = OFF_SH   + (size_t)NB*NC*NW; // [B][H][C]
static constexpr size_t OFF_PART = OFF_SW   + (size_t)NB*NH*NC; // [B][32][HW] s_sp partials
static constexpr size_t OFF_PSP  = OFF_PART + (size_t)NB*32*HW; // [B][HW]
static constexpr size_t OFF_PSH  = OFF_PSP  + (size_t)NB*HW;    // [B][C][W]
static constexpr size_t OFF_PSW  = OFF_PSH  + (size_t)NB*NC*NW; // [B][H][C]

// ---------------------------------------------------------------------------
// K1: one pass over x. Block = one (b,c) 64x64 plane (8192 blocks, 256 thr).
// Raw sums: csum[b][c], hsum[b][c][h] (over w), wsum[b][c][w] (over h).
// ---------------------------------------------------------------------------
__global__ __launch_bounds__(256) void k_stats(const float* __restrict__ x,
                                               float* __restrict__ ws) {
    const int bc = blockIdx.x;
    const int t  = threadIdx.x;
    const float4* plane = reinterpret_cast<const float4*>(x) + ((size_t)bc << 10);
    const float4 v0 = plane[t];
    const float4 v1 = plane[t + 256];
    const float4 v2 = plane[t + 512];
    const float4 v3 = plane[t + 768];
    const int h0 = t >> 4;

    float hp0 = v0.x + v0.y + v0.z + v0.w;
    float hp1 = v1.x + v1.y + v1.z + v1.w;
    float hp2 = v2.x + v2.y + v2.z + v2.w;
    float hp3 = v3.x + v3.y + v3.z + v3.w;
    #pragma unroll
    for (int d = 1; d < 16; d <<= 1) {
        hp0 += __shfl_xor(hp0, d);
        hp1 += __shfl_xor(hp1, d);
        hp2 += __shfl_xor(hp2, d);
        hp3 += __shfl_xor(hp3, d);
    }
    if ((t & 15) == 0) {
        float* hdst = ws + OFF_HSUM + (size_t)bc * NH;
        hdst[h0]      = hp0;
        hdst[h0 + 16] = hp1;
        hdst[h0 + 32] = hp2;
        hdst[h0 + 48] = hp3;
    }

    float4 wp;
    wp.x = v0.x + v1.x + v2.x + v3.x;
    wp.y = v0.y + v1.y + v2.y + v3.y;
    wp.z = v0.z + v1.z + v2.z + v3.z;
    wp.w = v0.w + v1.w + v2.w + v3.w;
    __shared__ float4 red4[256];
    red4[t] = wp;
    __syncthreads();
    for (int s2 = 128; s2 >= 16; s2 >>= 1) {
        if (t < s2) {
            red4[t].x += red4[t + s2].x;
            red4[t].y += red4[t + s2].y;
            red4[t].z += red4[t + s2].z;
            red4[t].w += red4[t + s2].w;
        }
        __syncthreads();
    }
    if (t < 16)
        reinterpret_cast<float4*>(ws + OFF_WSUM + (size_t)bc * NW)[t] = red4[t];
    if (t == 0) {
        float s = 0.f;
        #pragma unroll
        for (int i = 0; i < 16; ++i)
            s += red4[i].x + red4[i].y + red4[i].z + red4[i].w;
        ws[OFF_CSUM + bc] = s;
    }
}

// ---------------------------------------------------------------------------
// K2: tiny per-b kernel (32 blocks, 256 thr): means -> v_sp, v_h, v_w.
// ---------------------------------------------------------------------------
__global__ __launch_bounds__(256) void k_vecs(const float* __restrict__ wl1,
                                              const float* __restrict__ wl2,
                                              const float* __restrict__ wr1,
                                              const float* __restrict__ wr2,
                                              float* __restrict__ ws) {
    const int b = blockIdx.x, t = threadIdx.x;
    __shared__ float xbc[256], xbh[64], xbw[64], x2sp[128], th[32], tw[32];
    __shared__ float red[256];

    xbc[t] = ws[OFF_CSUM + (size_t)b * NC + t] * (1.0f / 4096.0f);

    {
        const int h = t & 63, part = t >> 6;
        float s = 0.f;
        const float* hs = ws + OFF_HSUM + ((size_t)b * NC + part * 64) * NH + h;
        for (int c = 0; c < 64; ++c) s += hs[(size_t)c * NH];
        red[t] = s;
        __syncthreads();
        if (t < 64) xbh[t] = (red[t] + red[t + 64] + red[t + 128] + red[t + 192]) * (1.0f / 16384.0f);
        __syncthreads();
    }
    {
        const int w = t & 63, part = t >> 6;
        float s = 0.f;
        const float* wsrc = ws + OFF_WSUM + ((size_t)b * NC + part * 64) * NW + w;
        for (int c = 0; c < 64; ++c) s += wsrc[(size_t)c * NW];
        red[t] = s;
        __syncthreads();
        if (t < 64) xbw[t] = (red[t] + red[t + 64] + red[t + 128] + red[t + 192]) * (1.0f / 16384.0f);
        __syncthreads();
    }

    if (t < 128) {
        float a = 0.f;
        for (int c = 0; c < 256; ++c) a += wl1[t * 256 + c] * xbc[c];
        x2sp[t] = a;
    } else if (t < 160) {
        const int m = t - 128;
        float a = 0.f;
        for (int h = 0; h < 64; ++h) a += wr1[m * 64 + h] * xbh[h];
        th[m] = a;
    } else if (t < 192) {
        const int m = t - 160;
        float a = 0.f;
        for (int h = 0; h < 64; ++h) a += wr1[m * 64 + h] * xbw[h];
        tw[m] = a;
    }
    __syncthreads();

    {
        float a = 0.f;
        for (int m = 0; m < 128; ++m) a += x2sp[m] * wl2[m * 256 + t];
        ws[OFF_VSP + (size_t)b * NC + t] = a;
    }
    if (t < 64) {
        float a = 0.f;
        for (int m = 0; m < 32; ++m) a += th[m] * wr2[m * 64 + t];
        ws[OFF_VH + (size_t)b * NH + t] = a;
    } else if (t < 128) {
        const int w = t - 64;
        float a = 0.f;
        for (int m = 0; m < 32; ++m) a += tw[m] * wr2[m * 64 + w];
        ws[OFF_VW + (size_t)b * NW + w] = a;
    }
}

// ---------------------------------------------------------------------------
// K3: second pass over x. 1024 blocks x 8 planes. Per plane: s_h[b][c][w],
// s_w[b][h][c]. Additionally each block accumulates its 8-channel partial of
// s_sp from the SAME loaded registers -> PART[b][strip=blk&31][4096].
// ---------------------------------------------------------------------------
__global__ __launch_bounds__(256) void k_scores(const float* __restrict__ x,
                                                float* __restrict__ ws) {
    const int t   = threadIdx.x;
    const int blk = blockIdx.x;
    const int b   = blk >> 5;          // 32 blocks per b
    const int h0  = t >> 4, w4 = t & 15;

    __shared__ float vh_s[64], vw_s[64], vsp_s[256];
    __shared__ float4 red4[256];

    if (t < 64)       vh_s[t]      = ws[OFF_VH + (size_t)b * NH + t];
    else if (t < 128) vw_s[t - 64] = ws[OFF_VW + (size_t)b * NW + (t - 64)];
    vsp_s[t] = ws[OFF_VSP + (size_t)b * NC + t];
    __syncthreads();

    float4 acc0 = make_float4(0.f,0.f,0.f,0.f);
    float4 acc1 = make_float4(0.f,0.f,0.f,0.f);
    float4 acc2 = make_float4(0.f,0.f,0.f,0.f);
    float4 acc3 = make_float4(0.f,0.f,0.f,0.f);

    for (int p = 0; p < 8; ++p) {
        const int bc = blk * 8 + p;
        const int c  = bc & 255;
        const float4* plane = reinterpret_cast<const float4*>(x) + ((size_t)bc << 10);
        const float4 v0 = plane[t];
        const float4 v1 = plane[t + 256];
        const float4 v2 = plane[t + 512];
        const float4 v3 = plane[t + 768];

        // s_w[b][h][c] = sum_w v_w[w]*x : shfl over 16 lanes sharing h
        const float4 vwv = reinterpret_cast<const float4*>(vw_s)[w4];
        float hp0 = vwv.x*v0.x + vwv.y*v0.y + vwv.z*v0.z + vwv.w*v0.w;
        float hp1 = vwv.x*v1.x + vwv.y*v1.y + vwv.z*v1.z + vwv.w*v1.w;
        float hp2 = vwv.x*v2.x + vwv.y*v2.y + vwv.z*v2.z + vwv.w*v2.w;
        float hp3 = vwv.x*v3.x + vwv.y*v3.y + vwv.z*v3.z + vwv.w*v3.w;
        #pragma unroll
        for (int d = 1; d < 16; d <<= 1) {
            hp0 += __shfl_xor(hp0, d);
            hp1 += __shfl_xor(hp1, d);
            hp2 += __shfl_xor(hp2, d);
            hp3 += __shfl_xor(hp3, d);
        }
        if (w4 == 0) {
            float* dst = ws + OFF_SW + (size_t)b * NH * NC + c;
            dst[(size_t)(h0)      * NC] = hp0;
            dst[(size_t)(h0 + 16) * NC] = hp1;
            dst[(size_t)(h0 + 32) * NC] = hp2;
            dst[(size_t)(h0 + 48) * NC] = hp3;
        }

        // s_h[b][c][w] = sum_h v_h[h]*x : LDS tree over 16 threads per w4
        const float a0 = vh_s[h0], a1 = vh_s[h0+16], a2 = vh_s[h0+32], a3 = vh_s[h0+48];
        float4 wp;
        wp.x = a0*v0.x + a1*v1.x + a2*v2.x + a3*v3.x;
        wp.y = a0*v0.y + a1*v1.y + a2*v2.y + a3*v3.y;
        wp.z = a0*v0.z + a1*v1.z + a2*v2.z + a3*v3.z;
        wp.w = a0*v0.w + a1*v1.w + a2*v2.w + a3*v3.w;
        red4[t] = wp;
        __syncthreads();
        for (int s2 = 128; s2 >= 16; s2 >>= 1) {
            if (t < s2) {
                red4[t].x += red4[t + s2].x;
                red4[t].y += red4[t + s2].y;
                red4[t].z += red4[t + s2].z;
                red4[t].w += red4[t + s2].w;
            }
            __syncthreads();
        }
        if (t < 16)
            reinterpret_cast<float4*>(ws + OFF_SH + (size_t)bc * NW)[t] = red4[t];
        __syncthreads();   // red4 reused next p

        // s_sp partial: no cross-thread reduction needed (cells are disjoint)
        const float vc = vsp_s[c];
        acc0.x += vc*v0.x; acc0.y += vc*v0.y; acc0.z += vc*v0.z; acc0.w += vc*v0.w;
        acc1.x += vc*v1.x; acc1.y += vc*v1.y; acc1.z += vc*v1.z; acc1.w += vc*v1.w;
        acc2.x += vc*v2.x; acc2.y += vc*v2.y; acc2.z += vc*v2.z; acc2.w += vc*v2.w;
        acc3.x += vc*v3.x; acc3.y += vc*v3.y; acc3.z += vc*v3.z; acc3.w += vc*v3.w;
    }

    // PART[b][strip][n]: thread t owns rows h0+16k, col-group w4 -> f4 idx t+256k
    float4* pf4 = reinterpret_cast<float4*>(ws + OFF_PART) +
                  ((size_t)b * 32 + (blk & 31)) * 1024;
    pf4[t]       = acc0;
    pf4[t + 256] = acc1;
    pf4[t + 512] = acc2;
    pf4[t + 768] = acc3;
}

// ---------------------------------------------------------------------------
// K4: softmax + sigmoid per (branch, b). 96 blocks. kind 0 first reduces the
// 32 s_sp partials into LDS, then softmaxes from LDS.
// ---------------------------------------------------------------------------
__global__ __launch_bounds__(256) void k_softmax(float* __restrict__ ws) {
    const int blk = blockIdx.x, t = threadIdx.x;
    const int kind = blk >> 5, b = blk & 31;
    __shared__ float red[256];
    __shared__ float4 ssp4[1024];   // 16 KB, used by kind 0 only

    if (kind == 0) {
        const float4* part = reinterpret_cast<const float4*>(ws + OFF_PART) +
                             (size_t)b * 32 * 1024;
        #pragma unroll
        for (int j = 0; j < 4; ++j) {
            const int n4 = j * 256 + t;
            float4 a = make_float4(0.f,0.f,0.f,0.f);
            for (int s = 0; s < 32; ++s) {
                const float4 v = part[(size_t)s * 1024 + n4];
                a.x += v.x; a.y += v.y; a.z += v.z; a.w += v.w;
            }
            ssp4[n4] = a;
        }
        __syncthreads();

        float mx = -3.4e38f;
        #pragma unroll
        for (int j = 0; j < 4; ++j) {
            const float4 v = ssp4[j * 256 + t];
            mx = fmaxf(mx, fmaxf(fmaxf(v.x, v.y), fmaxf(v.z, v.w)));
        }
        red[t] = mx;
        __syncthreads();
        for (int s = 128; s > 0; s >>= 1) {
            if (t < s) red[t] = fmaxf(red[t], red[t + s]);
            __syncthreads();
        }
        mx = red[0];
        __syncthreads();

        float sm = 0.f;
        #pragma unroll
        for (int j = 0; j < 4; ++j) {
            const float4 v = ssp4[j * 256 + t];
            sm += expf(v.x - mx) + expf(v.y - mx) + expf(v.z - mx) + expf(v.w - mx);
        }
        red[t] = sm;
        __syncthreads();
        for (int s = 128; s > 0; s >>= 1) {
            if (t < s) red[t] += red[t + s];
            __syncthreads();
        }
        const float inv = 1.0f / red[0];
        float4* dst = reinterpret_cast<float4*>(ws + OFF_PSP + (size_t)b * HW);
        #pragma unroll
        for (int j = 0; j < 4; ++j) {
            const float4 v = ssp4[j * 256 + t];
            float4 o;
            o.x = 1.0f / (1.0f + expf(-(expf(v.x - mx) * inv)));
            o.y = 1.0f / (1.0f + expf(-(expf(v.y - mx) * inv)));
            o.z = 1.0f / (1.0f + expf(-(expf(v.z - mx) * inv)));
            o.w = 1.0f / (1.0f + expf(-(expf(v.w - mx) * inv)));
            dst[j * 256 + t] = o;
        }
        return;
    }

    const float* src;
    float* dst;
    const int N = NC * NW;   // 16384 for both kinds 1 and 2
    if (kind == 1) { src = ws + OFF_SH + (size_t)b * NC * NW; dst = ws + OFF_PSH + (size_t)b * NC * NW; }
    else           { src = ws + OFF_SW + (size_t)b * NH * NC; dst = ws + OFF_PSW + (size_t)b * NH * NC; }

    float mx = -3.4e38f;
    for (int i = t; i < N; i += 256) mx = fmaxf(mx, src[i]);
    red[t] = mx;
    __syncthreads();
    for (int s = 128; s > 0; s >>= 1) {
        if (t < s) red[t] = fmaxf(red[t], red[t + s]);
        __syncthreads();
    }
    mx = red[0];
    __syncthreads();

    float sm = 0.f;
    for (int i = t; i < N; i += 256) sm += expf(src[i] - mx);
    red[t] = sm;
    __syncthreads();
    for (int s = 128; s > 0; s >>= 1) {
        if (t < s) red[t] += red[t + s];
        __syncthreads();
    }
    const float inv = 1.0f / red[0];
    for (int i = t; i < N; i += 256) {
        const float pr = expf(src[i] - mx) * inv;
        dst[i] = 1.0f / (1.0f + expf(-pr));
    }
}

// ---------------------------------------------------------------------------
// K5: out = x * (p_sp[b][h][w] + p_h[b][c][w] + p_w[b][h][c]).
// Non-temporal stores (native vector type) so out's 128MB doesn't evict the
// L3 copy of x serving this kernel's own reads.
// ---------------------------------------------------------------------------
__global__ __launch_bounds__(256) void k_final(const float* __restrict__ x,
                                               const float* __restrict__ ws,
                                               float* __restrict__ out) {
    const float* psp = ws + OFF_PSP;
    const float* psh = ws + OFF_PSH;
    const float* psw = ws + OFF_PSW;
    nfloat4* out4 = reinterpret_cast<nfloat4*>(out);
    size_t i4 = (size_t)blockIdx.x * 256 + threadIdx.x;
    #pragma unroll 4
    for (int it = 0; it < 16; ++it, i4 += (size_t)2048 * 256) {
        const int w4 = (int)(i4 & 15);
        const int h  = (int)((i4 >> 4) & 63);
        const int c  = (int)((i4 >> 10) & 255);
        const int b  = (int)(i4 >> 18);
        const float4 xv = reinterpret_cast<const float4*>(x)[i4];
        const float4 sp = reinterpret_cast<const float4*>(psp)[((size_t)b << 10) + (h << 4) + w4];
        const float4 sh = reinterpret_cast<const float4*>(psh)[(((size_t)b << 8) + c) * 16 + w4];
        const float  sw = psw[((size_t)b << 14) + (h << 8) + c];
        nfloat4 o;
        o.x = xv.x * (sp.x + sh.x + sw);
        o.y = xv.y * (sp.y + sh.y + sw);
        o.z = xv.z * (sp.z + sh.z + sw);
        o.w = xv.w * (sp.w + sh.w + sw);
        __builtin_nontemporal_store(o, &out4[i4]);
    }
}

extern "C" void kernel_launch(void* const* d_in, const int* in_sizes, int n_in,
                              void* d_out, int out_size, void* d_ws, size_t ws_size,
                              hipStream_t stream) {
    const float* x   = (const float*)d_in[0];
    const float* wl1 = (const float*)d_in[1];
    const float* wl2 = (const float*)d_in[2];
    const float* wr1 = (const float*)d_in[3];
    const float* wr2 = (const float*)d_in[4];
    float* out = (float*)d_out;
    float* ws  = (float*)d_ws;

    k_stats  <<<NB * NC, 256, 0, stream>>>(x, ws);
    k_vecs   <<<NB, 256, 0, stream>>>(wl1, wl2, wr1, wr2, ws);
    k_scores <<<1024, 256, 0, stream>>>(x, ws);
    k_softmax<<<3 * NB, 256, 0, stream>>>(ws);
    k_final  <<<2048, 256, 0, stream>>>(x, ws, out);
}